// Round 2
// baseline (592.231 us; speedup 1.0000x reference)
//
#include <hip/hip_runtime.h>
#include <math.h>

// Problem: N=8192 fp32. out = r_inv[:,None] * (a*b + I), r_inv = 1/rowsum(a*b+I), inf->0.
// One block per row: 256 threads x 8 float4 = 8192 floats = one full row.
//
// History:
//  - Baseline (191 us/disp): compiler REMATERIALIZED prod[] after the barrier
//    (VGPR=24 can't hold 32 floats) -> re-reads a,b from L2/L3. Total vmem
//    traffic 1.28 GB/disp = 6.7 TB/s = at the combined vmem ceiling.
//  - R1 (210 us/disp): asm pin made values opaque but the allocator SPILLED
//    to scratch instead of raising VGPRs (VGPR stayed 24; WRITE_SIZE leaked
//    +200KB of scratch evictions). Same 1.28 GB traffic, worse latency.
//  - R2 (this): stash products in LDS (32KB = full row). Thread-private
//    write/read-back, contiguous b128 (conflict-free), on-chip. Cuts vmem
//    traffic to 768 MB/disp. Costs occupancy (4 blocks/CU via LDS) --
//    compensated by batching all 16 global loads up front.

#define NDIM 8192
#define BLOCK 256
#define V4_PER_THREAD (NDIM / 4 / BLOCK)   // 8

typedef float f32x4 __attribute__((ext_vector_type(4)));

__global__ __launch_bounds__(BLOCK) void row_normalize_kernel(
    const float* __restrict__ a,
    const float* __restrict__ b,
    float* __restrict__ out)
{
    __shared__ f32x4 stash[NDIM / 4];          // 32 KB: the full product row
    __shared__ double wave_sums[BLOCK / 64];

    const int row = blockIdx.x;
    const int tid = threadIdx.x;

    const f32x4* __restrict__ a4 = (const f32x4*)(a + (size_t)row * NDIM);
    const f32x4* __restrict__ b4 = (const f32x4*)(b + (size_t)row * NDIM);
    float*       __restrict__ orow = out + (size_t)row * NDIM;

    // Batch ALL global loads first: 16 loads in flight per thread maximizes
    // bytes-in-flight at the LDS-capped occupancy (4 blocks/CU).
    f32x4 av[V4_PER_THREAD], bv[V4_PER_THREAD];
#pragma unroll
    for (int i = 0; i < V4_PER_THREAD; ++i)
        av[i] = a4[tid + i * BLOCK];           // coalesced: lane stride 16B
#pragma unroll
    for (int i = 0; i < V4_PER_THREAD; ++i)
        bv[i] = b4[tid + i * BLOCK];

    double sum = 0.0;
#pragma unroll
    for (int i = 0; i < V4_PER_THREAD; ++i) {
        const int idx = tid + i * BLOCK;
        f32x4 p = av[i] * bv[i];
        // identity: mx[row][row] += 1
        const int col0 = idx << 2;
        if ((unsigned)(row - col0) < 4u) {
            if      (row == col0)     p.x += 1.0f;
            else if (row == col0 + 1) p.y += 1.0f;
            else if (row == col0 + 2) p.z += 1.0f;
            else                      p.w += 1.0f;
        }
        stash[idx] = p;                        // thread-private stash, b128, no conflicts
        sum += (double)p.x + (double)p.y + (double)p.z + (double)p.w;
    }

    // wave-64 shuffle reduction
#pragma unroll
    for (int off = 32; off > 0; off >>= 1)
        sum += __shfl_down(sum, off, 64);

    const int lane = tid & 63;
    const int wave = tid >> 6;
    if (lane == 0) wave_sums[wave] = sum;
    __syncthreads();

    // Every thread computes the total redundantly: no second barrier.
    const double total = wave_sums[0] + wave_sums[1] + wave_sums[2] + wave_sums[3];
    float r_inv = 1.0f / (float)total;
    if (isinf(r_inv)) r_inv = 0.0f;

#pragma unroll
    for (int i = 0; i < V4_PER_THREAD; ++i) {
        const int idx = tid + i * BLOCK;
        f32x4 p = stash[idx];                  // read back own stash (on-chip)
        p *= r_inv;
        // streamed-once output: bypass cache allocation
        __builtin_nontemporal_store(p, (f32x4*)(orow + (idx << 2)));
    }
}

extern "C" void kernel_launch(void* const* d_in, const int* in_sizes, int n_in,
                              void* d_out, int out_size, void* d_ws, size_t ws_size,
                              hipStream_t stream) {
    const float* a = (const float*)d_in[0];   // estimated_adj
    const float* b = (const float*)d_in[1];   // ori
    float* out = (float*)d_out;
    row_normalize_kernel<<<NDIM, BLOCK, 0, stream>>>(a, b, out);
}

// Round 3
// 582.047 us; speedup vs baseline: 1.0175x; 1.0175x over previous
//
#include <hip/hip_runtime.h>
#include <math.h>

// Problem: N=8192 fp32. out = r_inv[:,None] * (a*b + I), r_inv = 1/rowsum(a*b+I), inf->0.
//
// History:
//  - R0 baseline (191 us/disp, 78% occ): compiler remat'd products after the
//    barrier -> 1.28 GB delivered vmem @ 6.7 TB/s.
//  - R1 (210 us): asm pin + NT stores. Same traffic, same occupancy, SLOWER.
//    NT stores are the prime suspect for the regression.
//  - R2 (214 us, 39% occ): LDS stash (32KB/block @ 256 thr) cut traffic to the
//    minimal 768 MB but halved occupancy -> delivered BW halved (3.6 TB/s).
//    Lesson: this kernel is LATENCY-bound; delivered BW ~ resident waves.
//  - R3 (this): same stash structure, BLOCK=512. Stash is per-ROW, so doubling
//    threads/block doubles waves per unit LDS: 4 blocks/CU x 8 waves = 32
//    waves/CU (100% occupancy). Plain stores (NT reverted).

#define NDIM 8192
#define BLOCK 512
#define V4_PER_THREAD (NDIM / 4 / BLOCK)   // 4
#define WAVES (BLOCK / 64)                 // 8

typedef float f32x4 __attribute__((ext_vector_type(4)));

__global__ __launch_bounds__(BLOCK, 8) void row_normalize_kernel(
    const float* __restrict__ a,
    const float* __restrict__ b,
    float* __restrict__ out)
{
    __shared__ f32x4 stash[NDIM / 4];          // 32 KB: the full product row
    __shared__ double wave_sums[WAVES];

    const int row = blockIdx.x;
    const int tid = threadIdx.x;

    const f32x4* __restrict__ a4 = (const f32x4*)(a + (size_t)row * NDIM);
    const f32x4* __restrict__ b4 = (const f32x4*)(b + (size_t)row * NDIM);
    f32x4*       __restrict__ o4 = (f32x4*)(out + (size_t)row * NDIM);

    // Batch all global loads up front: 8 x 16B in flight per thread.
    f32x4 av[V4_PER_THREAD], bv[V4_PER_THREAD];
#pragma unroll
    for (int i = 0; i < V4_PER_THREAD; ++i)
        av[i] = a4[tid + i * BLOCK];           // coalesced: lane stride 16B
#pragma unroll
    for (int i = 0; i < V4_PER_THREAD; ++i)
        bv[i] = b4[tid + i * BLOCK];

    double sum = 0.0;
#pragma unroll
    for (int i = 0; i < V4_PER_THREAD; ++i) {
        const int idx = tid + i * BLOCK;
        f32x4 p = av[i] * bv[i];
        // identity: mx[row][row] += 1
        const int col0 = idx << 2;
        if ((unsigned)(row - col0) < 4u) {
            if      (row == col0)     p.x += 1.0f;
            else if (row == col0 + 1) p.y += 1.0f;
            else if (row == col0 + 2) p.z += 1.0f;
            else                      p.w += 1.0f;
        }
        stash[idx] = p;                        // thread-private stash, b128, conflict-free
        sum += (double)p.x + (double)p.y + (double)p.z + (double)p.w;
    }

    // wave-64 shuffle reduction
#pragma unroll
    for (int off = 32; off > 0; off >>= 1)
        sum += __shfl_down(sum, off, 64);

    const int lane = tid & 63;
    const int wave = tid >> 6;
    if (lane == 0) wave_sums[wave] = sum;
    __syncthreads();

    // Every thread computes the total redundantly (LDS broadcast reads).
    double total = 0.0;
#pragma unroll
    for (int w = 0; w < WAVES; ++w) total += wave_sums[w];
    float r_inv = 1.0f / (float)total;
    if (isinf(r_inv)) r_inv = 0.0f;

#pragma unroll
    for (int i = 0; i < V4_PER_THREAD; ++i) {
        const int idx = tid + i * BLOCK;
        f32x4 p = stash[idx];                  // read back own stash (on-chip)
        p *= r_inv;
        o4[idx] = p;                           // plain store (NT regressed in R1)
    }
}

extern "C" void kernel_launch(void* const* d_in, const int* in_sizes, int n_in,
                              void* d_out, int out_size, void* d_ws, size_t ws_size,
                              hipStream_t stream) {
    const float* a = (const float*)d_in[0];   // estimated_adj
    const float* b = (const float*)d_in[1];   // ori
    float* out = (float*)d_out;
    row_normalize_kernel<<<NDIM, BLOCK, 0, stream>>>(a, b, out);
}

// Round 4
// 580.385 us; speedup vs baseline: 1.0204x; 1.0029x over previous
//
#include <hip/hip_runtime.h>
#include <math.h>

// Problem: N=8192 fp32. out = r_inv[:,None] * (a*b + I), r_inv = 1/rowsum(a*b+I), inf->0.
//
// History:
//  - R0 baseline (191 us): remat'd products -> 1.28 GB vmem. VGPR=24.
//  - R1 (210 us): asm pin -> scratch spill. VGPR=24.
//  - R2 (214 us, 39% occ): LDS stash @ 256thr; minimal traffic but LDS-capped occupancy.
//  - R3 (192 us, 78% occ): LDS stash @ 512thr. Occupancy fixed, STILL 192 us. VGPR=20:
//    allocator serialized the "batched" loads -> ~2 loads in flight/wave. Every round's
//    MLP has been capped by register allocation.
//  - R4 (this): async DMA staging. global_load_lds needs NO dest VGPRs: each wave puts
//    4 KiB in flight back-to-back (128 KiB/CU) regardless of the allocator. Both input
//    rows staged to LDS; products overwrite the A buffer in place; post-barrier phase
//    is pure LDS-read + store. BLOCK=1024, 64 KiB LDS, 2 blocks/CU = 32 waves/CU.

#define NDIM 8192
#define BLOCK 1024
#define WAVES (BLOCK / 64)                  // 16
#define V4_PER_THREAD (NDIM / 4 / BLOCK)    // 2
#define ROW_BYTES (NDIM * 4)                // 32768
#define CHUNK_BYTES 1024                    // one wave-DMA: 64 lanes x 16 B
#define CHUNKS (ROW_BYTES / CHUNK_BYTES)    // 32
#define CHUNKS_PER_WAVE (CHUNKS / WAVES)    // 2

typedef float f32x4 __attribute__((ext_vector_type(4)));
typedef __attribute__((address_space(3))) unsigned int lds_u32;
typedef const __attribute__((address_space(1))) unsigned int glb_u32;

__device__ __forceinline__ void dma16(const void* g, void* lds) {
    // width=16: lane l loads 16 B from its own gaddr into (uniform lds base + l*16).
    __builtin_amdgcn_global_load_lds((glb_u32*)g, (lds_u32*)lds, 16, 0, 0);
}

__global__ __launch_bounds__(BLOCK, 8) void row_normalize_kernel(
    const float* __restrict__ a,
    const float* __restrict__ b,
    float* __restrict__ out)
{
    __shared__ f32x4 bufA[NDIM / 4];        // 32 KiB: a-row, then product (in place)
    __shared__ f32x4 bufB[NDIM / 4];        // 32 KiB: b-row
    __shared__ double wave_sums[WAVES];

    const int row  = blockIdx.x;
    const int tid  = threadIdx.x;
    const int lane = tid & 63;
    const int wave = tid >> 6;

    const char* arow = (const char*)(a + (size_t)row * NDIM);
    const char* brow = (const char*)(b + (size_t)row * NDIM);
    f32x4* __restrict__ o4 = (f32x4*)(out + (size_t)row * NDIM);

    // --- Stage both rows via async DMA: no dest VGPRs, full MLP by construction.
#pragma unroll
    for (int k = 0; k < CHUNKS_PER_WAVE; ++k) {
        const int c = wave * CHUNKS_PER_WAVE + k;
        const int goff = c * CHUNK_BYTES + lane * 16;   // per-lane global addr
        dma16(arow + goff, (char*)bufA + c * CHUNK_BYTES);
        dma16(brow + goff, (char*)bufB + c * CHUNK_BYTES);
    }
    asm volatile("s_waitcnt vmcnt(0)" ::: "memory");
    __syncthreads();

    // --- Product + row-sum. Overwrite bufA with the product (thread-private slots).
    double sum = 0.0;
#pragma unroll
    for (int i = 0; i < V4_PER_THREAD; ++i) {
        const int idx = tid + i * BLOCK;
        f32x4 p = bufA[idx] * bufB[idx];
        // identity: mx[row][row] += 1
        const int col0 = idx << 2;
        if ((unsigned)(row - col0) < 4u) {
            if      (row == col0)     p.x += 1.0f;
            else if (row == col0 + 1) p.y += 1.0f;
            else if (row == col0 + 2) p.z += 1.0f;
            else                      p.w += 1.0f;
        }
        bufA[idx] = p;
        sum += (double)p.x + (double)p.y + (double)p.z + (double)p.w;
    }

    // wave-64 shuffle reduction
#pragma unroll
    for (int off = 32; off > 0; off >>= 1)
        sum += __shfl_down(sum, off, 64);

    if (lane == 0) wave_sums[wave] = sum;
    __syncthreads();

    // Every thread computes the total redundantly (LDS broadcast reads).
    double total = 0.0;
#pragma unroll
    for (int w = 0; w < WAVES; ++w) total += wave_sums[w];
    float r_inv = 1.0f / (float)total;
    if (isinf(r_inv)) r_inv = 0.0f;

    // --- Scale + store: pure LDS-read + store burst.
#pragma unroll
    for (int i = 0; i < V4_PER_THREAD; ++i) {
        const int idx = tid + i * BLOCK;
        f32x4 p = bufA[idx];
        p *= r_inv;
        o4[idx] = p;
    }
}

extern "C" void kernel_launch(void* const* d_in, const int* in_sizes, int n_in,
                              void* d_out, int out_size, void* d_ws, size_t ws_size,
                              hipStream_t stream) {
    const float* a = (const float*)d_in[0];   // estimated_adj
    const float* b = (const float*)d_in[1];   // ori
    float* out = (float*)d_out;
    row_normalize_kernel<<<NDIM, BLOCK, 0, stream>>>(a, b, out);
}